// Round 1
// 352.899 us; speedup vs baseline: 1.0151x; 1.0151x over previous
//
#include <hip/hip_runtime.h>
#include <math.h>

// ---------------------------------------------------------------------------
// Segmented softmax: softmax within each contiguous n-best group.
// scores: float32[TOTAL], nBestIndex: int32[NUM_SEG], out: float32[TOTAL].
// Offsets = exclusive prefix sum of nBestIndex (ragged in general).
//
// R3 design: 16-lane sub-group per segment, values held in REGISTERS
// (up to 4 elements/lane -> covers c <= 64, which includes the N=50 case).
// Reductions via __shfl_xor at width 16 -- no LDS, no bank conflicts, no
// serial per-segment loop. Segments with c > 64 fall back to a strided
// 3-pass global-memory path per group (rare; L2/L3 absorbs re-reads).
//
// Prior R2 (LDS-staged, 1 thread/segment serial 3-pass) was 122 us at
// 2.48 TB/s: bound by serial LDS ops + 4-way bank conflicts, not HBM.
// ---------------------------------------------------------------------------

#define GSEG 16                       // lanes per segment group
#define SBLOCK 256                    // threads per softmax block
#define SEG_PER_BLOCK (SBLOCK / GSEG) // 16 segments per block

// Kernel A: per-block (256-wide) exclusive scan of counts; block totals out.
__global__ __launch_bounds__(256) void scan_local_kernel(
    const int* __restrict__ counts, int n_seg,
    int* __restrict__ local_scan, int* __restrict__ block_sums) {
    __shared__ int sm[256];
    const int t = threadIdx.x;
    const int g = blockIdx.x * 256 + t;
    const int v = (g < n_seg) ? counts[g] : 0;
    sm[t] = v;
    __syncthreads();
    for (int off = 1; off < 256; off <<= 1) {
        int y = (t >= off) ? sm[t - off] : 0;
        __syncthreads();
        sm[t] += y;
        __syncthreads();
    }
    if (g < n_seg) local_scan[g] = sm[t] - v;   // exclusive within block
    if (t == 255) block_sums[blockIdx.x] = sm[255];
}

// Kernel B: single-block exclusive scan of block_sums in place.
__global__ __launch_bounds__(256) void scan_bsums_kernel(
    int* __restrict__ bsum, int nb) {
    __shared__ int sm[256];
    const int t = threadIdx.x;
    const int per = (nb + 255) >> 8;
    const int beg = t * per;
    const int end = (beg + per < nb) ? beg + per : nb;
    int tot = 0;
    for (int j = beg; j < end; ++j) tot += bsum[j];
    sm[t] = tot;
    __syncthreads();
    for (int off = 1; off < 256; off <<= 1) {
        int y = (t >= off) ? sm[t - off] : 0;
        __syncthreads();
        sm[t] += y;
        __syncthreads();
    }
    int run = sm[t] - tot;
    for (int j = beg; j < end; ++j) {
        int v = bsum[j];
        bsum[j] = run;
        run += v;
    }
}

// Kernel C: register-resident segmented softmax, 16 lanes per segment.
__global__ __launch_bounds__(SBLOCK) void seg_softmax_kernel(
    const float* __restrict__ scores,
    const int* __restrict__ local_scan, const int* __restrict__ bsum,
    float* __restrict__ out, int n_seg, int total) {
    const int tid = threadIdx.x;
    const int p   = tid & (GSEG - 1);                 // lane within group
    const int seg = blockIdx.x * SEG_PER_BLOCK + (tid >> 4);
    if (seg >= n_seg) return;

    const int st = local_scan[seg] + bsum[seg >> 8];
    int en;
    if (seg + 1 < n_seg) en = local_scan[seg + 1] + bsum[(seg + 1) >> 8];
    else                 en = total;
    const int c = en - st;
    if (c <= 0) return;

    if (c <= 4 * GSEG) {
        // ---- fast path: up to 64 elements live in 4 registers/lane ----
        const int i0 = p, i1 = p + GSEG, i2 = p + 2 * GSEG, i3 = p + 3 * GSEG;
        float v0 = -INFINITY, v1 = -INFINITY, v2 = -INFINITY, v3 = -INFINITY;
        if (i0 < c) v0 = scores[st + i0];
        if (i1 < c) v1 = scores[st + i1];
        if (i2 < c) v2 = scores[st + i2];
        if (i3 < c) v3 = scores[st + i3];

        float m = fmaxf(fmaxf(v0, v1), fmaxf(v2, v3));
        #pragma unroll
        for (int off = 1; off < GSEG; off <<= 1)
            m = fmaxf(m, __shfl_xor(m, off, GSEG));

        // exp(-INF - m) == 0, so inactive slots contribute nothing.
        v0 = __expf(v0 - m);
        v1 = __expf(v1 - m);
        v2 = __expf(v2 - m);
        v3 = __expf(v3 - m);
        float s = (v0 + v1) + (v2 + v3);
        #pragma unroll
        for (int off = 1; off < GSEG; off <<= 1)
            s += __shfl_xor(s, off, GSEG);

        const float inv = 1.0f / s;
        if (i0 < c) out[st + i0] = v0 * inv;
        if (i1 < c) out[st + i1] = v1 * inv;
        if (i2 < c) out[st + i2] = v2 * inv;
        if (i3 < c) out[st + i3] = v3 * inv;
    } else {
        // ---- slow path: big segment, strided 3-pass over global memory ----
        float m = -INFINITY;
        for (int j = p; j < c; j += GSEG)
            m = fmaxf(m, scores[st + j]);
        #pragma unroll
        for (int off = 1; off < GSEG; off <<= 1)
            m = fmaxf(m, __shfl_xor(m, off, GSEG));

        float s = 0.0f;
        for (int j = p; j < c; j += GSEG)
            s += __expf(scores[st + j] - m);
        #pragma unroll
        for (int off = 1; off < GSEG; off <<= 1)
            s += __shfl_xor(s, off, GSEG);

        const float inv = 1.0f / s;
        for (int j = p; j < c; j += GSEG)
            out[st + j] = __expf(scores[st + j] - m) * inv;
    }
}

extern "C" void kernel_launch(void* const* d_in, const int* in_sizes, int n_in,
                              void* d_out, int out_size, void* d_ws, size_t ws_size,
                              hipStream_t stream) {
    const float* scores = (const float*)d_in[0];
    const int*   counts = (const int*)d_in[1];
    float* out = (float*)d_out;
    const int n_seg = in_sizes[1];
    const int total = in_sizes[0];

    // Workspace layout: [n_seg] local exclusive scan | [nblocksA] block sums
    int* local_scan = (int*)d_ws;
    const int nblocksA = (n_seg + 255) / 256;
    int* block_sums = local_scan + n_seg;

    scan_local_kernel<<<nblocksA, 256, 0, stream>>>(counts, n_seg, local_scan, block_sums);
    scan_bsums_kernel<<<1, 256, 0, stream>>>(block_sums, nblocksA);

    const int nblocksC = (n_seg + SEG_PER_BLOCK - 1) / SEG_PER_BLOCK;
    seg_softmax_kernel<<<nblocksC, SBLOCK, 0, stream>>>(
        scores, local_scan, block_sums, out, n_seg, total);
}